// Round 1
// baseline (1596.378 us; speedup 1.0000x reference)
//
#include <hip/hip_runtime.h>

#define HID 128
#define HID2 256

// ---------------- kernel 1: h = PReLU(x) @ W_enc^T ----------------
// grid: ceil(N/16), block 256. Stages 16 PReLU'd x-rows in LDS.
__global__ __launch_bounds__(256) void k_enc(const float* __restrict__ x,
                                             const float* __restrict__ W,
                                             const float* __restrict__ pa,
                                             float* __restrict__ h, int N) {
    __shared__ float xs[16][HID];   // 8 KB
    const int bn = blockIdx.x * 16;
    const int t  = threadIdx.x;
    const float a = pa[0];
    for (int i = t; i < 16 * HID; i += 256) {
        int r = i >> 7, c = i & 127;
        int row = bn + r;
        float v = (row < N) ? x[row * HID + c] : 0.f;
        xs[r][c] = v > 0.f ? v : a * v;
    }
    __syncthreads();
    const int col = t & 127;
    const int ng  = t >> 7;          // 0 or 1
    float acc[8];
#pragma unroll
    for (int i = 0; i < 8; ++i) acc[i] = 0.f;
    const float* wrow = W + col * HID;
    for (int k = 0; k < HID; k += 4) {
        float4 w = *(const float4*)(wrow + k);
#pragma unroll
        for (int i = 0; i < 8; ++i) {
            int n = ng + 2 * i;
            acc[i] += w.x * xs[n][k] + w.y * xs[n][k + 1] +
                      w.z * xs[n][k + 2] + w.w * xs[n][k + 3];
        }
    }
#pragma unroll
    for (int i = 0; i < 8; ++i) {
        int row = bn + ng + 2 * i;
        if (row < N) h[row * HID + col] = acc[i];
    }
}

// ---------------- kernel 2: zero masked rows ----------------
__global__ void k_mask(const int* __restrict__ idx, float* __restrict__ h) {
    h[idx[blockIdx.x] * HID + threadIdx.x] = 0.f;
}

// ---------------- kernel 3: combo[i][j] = emb1[i] + emb2[j] ----------------
// grid 18 (6*3), block 128
__global__ void k_combo(const float* __restrict__ e1, const float* __restrict__ e2,
                        float* __restrict__ combo) {
    int i = blockIdx.x / 3, j = blockIdx.x % 3, c = threadIdx.x;
    combo[blockIdx.x * HID + c] = e1[i * HID + c] + e2[j * HID + c];
}

// ---------------- kernel 4: aggr = h + combo[4,0]  (self loops) ----------------
__global__ __launch_bounds__(256) void k_init(const float* __restrict__ h,
                                              const float* __restrict__ combo,
                                              float* __restrict__ aggr, int total) {
    int i = blockIdx.x * 256 + threadIdx.x;
    if (i < total) {
        int c = i & 127;
        aggr[i] = h[i] + combo[12 * HID + c];   // combo idx 4*3+0
    }
}

// ---------------- kernel 5: edge scatter ----------------
// thread = (edge, 4-channel chunk): tid>>5 = edge, (tid&31)*4 = channel base
__global__ __launch_bounds__(256) void k_scatter(const float* __restrict__ h,
                                                 const int* __restrict__ src,
                                                 const int* __restrict__ dst,
                                                 const int* __restrict__ ea,
                                                 const float* __restrict__ combo,
                                                 float* __restrict__ aggr, int E) {
    int tid = blockIdx.x * 256 + threadIdx.x;
    int e = tid >> 5;
    if (e >= E) return;
    int q = (tid & 31) << 2;
    int s  = src[e], d = dst[e];
    int a0 = ea[2 * e], a1 = ea[2 * e + 1];
    float4 hv = *(const float4*)(h + s * HID + q);
    float4 cv = *(const float4*)(combo + (a0 * 3 + a1) * HID + q);
    float* p = aggr + d * HID + q;
    atomicAdd(p + 0, hv.x + cv.x);
    atomicAdd(p + 1, hv.y + cv.y);
    atomicAdd(p + 2, hv.z + cv.z);
    atomicAdd(p + 3, hv.w + cv.w);
}

// ---------------- kernel 6: out = relu(aggr@W1^T+b1)@W2^T+b2, in place ----------------
// grid ceil(N/16), block 256
__global__ __launch_bounds__(256) void k_mlp(float* __restrict__ io,
                                             const float* __restrict__ W1,
                                             const float* __restrict__ b1,
                                             const float* __restrict__ W2,
                                             const float* __restrict__ b2, int N) {
    __shared__ float as[16][HID];    // 8 KB
    __shared__ float hs[16][HID2];   // 16 KB
    const int bn = blockIdx.x * 16;
    const int t  = threadIdx.x;
    for (int i = t; i < 16 * HID; i += 256) {
        int r = i >> 7, c = i & 127;
        int row = bn + r;
        as[r][c] = (row < N) ? io[row * HID + c] : 0.f;
    }
    __syncthreads();
    // phase 1: hidden[n][t] for n=0..15
    {
        float acc[16];
#pragma unroll
        for (int i = 0; i < 16; ++i) acc[i] = 0.f;
        const float* w = W1 + t * HID;
        for (int k = 0; k < HID; k += 4) {
            float4 wv = *(const float4*)(w + k);
#pragma unroll
            for (int n = 0; n < 16; ++n) {
                acc[n] += wv.x * as[n][k] + wv.y * as[n][k + 1] +
                          wv.z * as[n][k + 2] + wv.w * as[n][k + 3];
            }
        }
        float bb = b1[t];
#pragma unroll
        for (int n = 0; n < 16; ++n) {
            float v = acc[n] + bb;
            hs[n][t] = v > 0.f ? v : 0.f;
        }
    }
    __syncthreads();
    // phase 2: out[n][col], col = t&127, n = (t>>7)+2*i
    {
        const int col = t & 127;
        const int ng  = t >> 7;
        float acc[8];
#pragma unroll
        for (int i = 0; i < 8; ++i) acc[i] = 0.f;
        const float* w = W2 + col * HID2;
        for (int k = 0; k < HID2; k += 4) {
            float4 wv = *(const float4*)(w + k);
#pragma unroll
            for (int i = 0; i < 8; ++i) {
                int n = ng + 2 * i;
                acc[i] += wv.x * hs[n][k] + wv.y * hs[n][k + 1] +
                          wv.z * hs[n][k + 2] + wv.w * hs[n][k + 3];
            }
        }
        float bb = b2[col];
#pragma unroll
        for (int i = 0; i < 8; ++i) {
            int row = bn + ng + 2 * i;
            if (row < N) io[row * HID + col] = acc[i] + bb;
        }
    }
}

extern "C" void kernel_launch(void* const* d_in, const int* in_sizes, int n_in,
                              void* d_out, int out_size, void* d_ws, size_t ws_size,
                              hipStream_t stream) {
    const float* x     = (const float*)d_in[0];
    const int*   eidx  = (const int*)d_in[1];
    const int*   eattr = (const int*)d_in[2];
    const int*   mask  = (const int*)d_in[3];
    const float* pa    = (const float*)d_in[4];
    const float* Wenc  = (const float*)d_in[5];
    const float* W1    = (const float*)d_in[6];
    const float* b1    = (const float*)d_in[7];
    const float* W2    = (const float*)d_in[8];
    const float* b2    = (const float*)d_in[9];
    const float* emb1  = (const float*)d_in[10];
    const float* emb2  = (const float*)d_in[11];

    const int N = in_sizes[0] / HID;     // 50000
    const int E = in_sizes[1] / 2;       // 800000
    const int M = in_sizes[3];           // 5000

    const int* src = eidx;
    const int* dst = eidx + E;

    float* h     = (float*)d_ws;                       // N*HID f32
    float* combo = (float*)((char*)d_ws + (size_t)N * HID * sizeof(float)); // 18*HID
    float* aggr  = (float*)d_out;                      // reused in-place by k_mlp

    const int nb16 = (N + 15) / 16;

    k_enc<<<nb16, 256, 0, stream>>>(x, Wenc, pa, h, N);
    k_mask<<<M, HID, 0, stream>>>(mask, h);
    k_combo<<<18, HID, 0, stream>>>(emb1, emb2, combo);
    k_init<<<(N * HID + 255) / 256, 256, 0, stream>>>(h, combo, aggr, N * HID);
    k_scatter<<<(E * 32 + 255) / 256, 256, 0, stream>>>(h, src, dst, eattr, combo, aggr, E);
    k_mlp<<<nb16, 256, 0, stream>>>(aggr, W1, b1, W2, b2, N);
}

// Round 2
// 478.741 us; speedup vs baseline: 3.3345x; 3.3345x over previous
//
#include <hip/hip_runtime.h>

#define HID 128
#define HID2 256

// ---------------- kernel 1: h = PReLU(x) @ W_enc^T ----------------
__global__ __launch_bounds__(256) void k_enc(const float* __restrict__ x,
                                             const float* __restrict__ W,
                                             const float* __restrict__ pa,
                                             float* __restrict__ h, int N) {
    __shared__ float xs[16][HID];
    const int bn = blockIdx.x * 16;
    const int t  = threadIdx.x;
    const float a = pa[0];
    for (int i = t; i < 16 * HID; i += 256) {
        int r = i >> 7, c = i & 127;
        int row = bn + r;
        float v = (row < N) ? x[row * HID + c] : 0.f;
        xs[r][c] = v > 0.f ? v : a * v;
    }
    __syncthreads();
    const int col = t & 127;
    const int ng  = t >> 7;
    float acc[8];
#pragma unroll
    for (int i = 0; i < 8; ++i) acc[i] = 0.f;
    const float* wrow = W + col * HID;
    for (int k = 0; k < HID; k += 4) {
        float4 w = *(const float4*)(wrow + k);
#pragma unroll
        for (int i = 0; i < 8; ++i) {
            int n = ng + 2 * i;
            acc[i] += w.x * xs[n][k] + w.y * xs[n][k + 1] +
                      w.z * xs[n][k + 2] + w.w * xs[n][k + 3];
        }
    }
#pragma unroll
    for (int i = 0; i < 8; ++i) {
        int row = bn + ng + 2 * i;
        if (row < N) h[row * HID + col] = acc[i];
    }
}

// ---------------- kernel 2: zero masked rows ----------------
__global__ void k_mask(const int* __restrict__ idx, float* __restrict__ h) {
    h[idx[blockIdx.x] * HID + threadIdx.x] = 0.f;
}

// ---------------- kernel 3: combo[i][j] = emb1[i] + emb2[j] ----------------
__global__ void k_combo(const float* __restrict__ e1, const float* __restrict__ e2,
                        float* __restrict__ combo) {
    int i = blockIdx.x / 3, j = blockIdx.x % 3, c = threadIdx.x;
    combo[blockIdx.x * HID + c] = e1[i * HID + c] + e2[j * HID + c];
}

// ---------------- kernel 4: zero int scratch ----------------
__global__ __launch_bounds__(256) void k_zero(int* __restrict__ p, int n) {
    int i = blockIdx.x * 256 + threadIdx.x;
    if (i < n) p[i] = 0;
}

// ---------------- kernel 5: histogram of dst ----------------
__global__ __launch_bounds__(256) void k_hist(const int* __restrict__ dst,
                                              int* __restrict__ cnt, int E) {
    int e = blockIdx.x * 256 + threadIdx.x;
    if (e < E) atomicAdd(&cnt[dst[e]], 1);
}

// ---------------- kernel 6: exclusive scan over N counts (1 block, 1024 thr) ----------------
__global__ __launch_bounds__(1024) void k_scan(const int* __restrict__ cnt,
                                               int* __restrict__ offs, int N) {
    __shared__ int ls[1024];
    const int t = threadIdx.x;
    const int chunk = (N + 1023) / 1024;
    const int begin = t * chunk;
    const int end   = min(begin + chunk, N);
    int s = 0;
    for (int i = begin; i < end; ++i) s += cnt[i];
    ls[t] = s;
    __syncthreads();
    // inclusive Hillis-Steele scan over ls
    for (int off = 1; off < 1024; off <<= 1) {
        int u = (t >= off) ? ls[t - off] : 0;
        __syncthreads();
        ls[t] += u;
        __syncthreads();
    }
    int run = (t == 0) ? 0 : ls[t - 1];
    for (int i = begin; i < end; ++i) {
        offs[i] = run;
        run += cnt[i];
    }
}

// ---------------- kernel 7: scatter edge ids into dst-sorted order ----------------
__global__ __launch_bounds__(256) void k_place(const int* __restrict__ dst,
                                               const int* __restrict__ offs,
                                               int* __restrict__ cursor,
                                               int* __restrict__ sorted, int E) {
    int e = blockIdx.x * 256 + threadIdx.x;
    if (e < E) {
        int d = dst[e];
        int pos = offs[d] + atomicAdd(&cursor[d], 1);
        sorted[pos] = e;
    }
}

// ---------------- kernel 8: per-node gather-accumulate (incl. self loop) ----------------
// grid N, block 128; thread = channel
__global__ __launch_bounds__(128) void k_gather(const float* __restrict__ h,
                                                const int* __restrict__ src,
                                                const int* __restrict__ ea,
                                                const float* __restrict__ combo,
                                                const int* __restrict__ offs,
                                                const int* __restrict__ cnt,
                                                const int* __restrict__ sorted,
                                                float* __restrict__ out) {
    __shared__ int s_src[128];
    __shared__ int s_cmb[128];
    const int n = blockIdx.x;
    const int c = threadIdx.x;
    const int start = offs[n];
    const int deg   = cnt[n];
    // self loop: h[n] + combo[4*3+0]
    float acc = h[n * HID + c] + combo[12 * HID + c];
    for (int base = 0; base < deg; base += 128) {
        int m = min(128, deg - base);
        if (c < m) {
            int e = sorted[start + base + c];
            s_src[c] = src[e];
            s_cmb[c] = ea[2 * e] * 3 + ea[2 * e + 1];
        }
        __syncthreads();
#pragma unroll 4
        for (int k = 0; k < m; ++k) {
            acc += h[s_src[k] * HID + c] + combo[s_cmb[k] * HID + c];
        }
        __syncthreads();
    }
    out[n * HID + c] = acc;
}

// ---------------- kernel 9: out = relu(aggr@W1^T+b1)@W2^T+b2, in place ----------------
__global__ __launch_bounds__(256) void k_mlp(float* __restrict__ io,
                                             const float* __restrict__ W1,
                                             const float* __restrict__ b1,
                                             const float* __restrict__ W2,
                                             const float* __restrict__ b2, int N) {
    __shared__ float as[16][HID];
    __shared__ float hs[16][HID2];
    const int bn = blockIdx.x * 16;
    const int t  = threadIdx.x;
    for (int i = t; i < 16 * HID; i += 256) {
        int r = i >> 7, c = i & 127;
        int row = bn + r;
        as[r][c] = (row < N) ? io[row * HID + c] : 0.f;
    }
    __syncthreads();
    {
        float acc[16];
#pragma unroll
        for (int i = 0; i < 16; ++i) acc[i] = 0.f;
        const float* w = W1 + t * HID;
        for (int k = 0; k < HID; k += 4) {
            float4 wv = *(const float4*)(w + k);
#pragma unroll
            for (int n = 0; n < 16; ++n) {
                acc[n] += wv.x * as[n][k] + wv.y * as[n][k + 1] +
                          wv.z * as[n][k + 2] + wv.w * as[n][k + 3];
            }
        }
        float bb = b1[t];
#pragma unroll
        for (int n = 0; n < 16; ++n) {
            float v = acc[n] + bb;
            hs[n][t] = v > 0.f ? v : 0.f;
        }
    }
    __syncthreads();
    {
        const int col = t & 127;
        const int ng  = t >> 7;
        float acc[8];
#pragma unroll
        for (int i = 0; i < 8; ++i) acc[i] = 0.f;
        const float* w = W2 + col * HID2;
        for (int k = 0; k < HID2; k += 4) {
            float4 wv = *(const float4*)(w + k);
#pragma unroll
            for (int i = 0; i < 8; ++i) {
                int n = ng + 2 * i;
                acc[i] += wv.x * hs[n][k] + wv.y * hs[n][k + 1] +
                          wv.z * hs[n][k + 2] + wv.w * hs[n][k + 3];
            }
        }
        float bb = b2[col];
#pragma unroll
        for (int i = 0; i < 8; ++i) {
            int row = bn + ng + 2 * i;
            if (row < N) io[row * HID + col] = acc[i] + bb;
        }
    }
}

extern "C" void kernel_launch(void* const* d_in, const int* in_sizes, int n_in,
                              void* d_out, int out_size, void* d_ws, size_t ws_size,
                              hipStream_t stream) {
    const float* x     = (const float*)d_in[0];
    const int*   eidx  = (const int*)d_in[1];
    const int*   eattr = (const int*)d_in[2];
    const int*   mask  = (const int*)d_in[3];
    const float* pa    = (const float*)d_in[4];
    const float* Wenc  = (const float*)d_in[5];
    const float* W1    = (const float*)d_in[6];
    const float* b1    = (const float*)d_in[7];
    const float* W2    = (const float*)d_in[8];
    const float* b2    = (const float*)d_in[9];
    const float* emb1  = (const float*)d_in[10];
    const float* emb2  = (const float*)d_in[11];

    const int N = in_sizes[0] / HID;     // 50000
    const int E = in_sizes[1] / 2;       // 800000
    const int M = in_sizes[3];           // 5000

    const int* src = eidx;
    const int* dst = eidx + E;

    // workspace layout
    float* h      = (float*)d_ws;                        // N*HID
    float* combo  = h + (size_t)N * HID;                 // 18*HID
    int*   cnt    = (int*)(combo + 18 * HID);            // N
    int*   cursor = cnt + N;                             // N
    int*   offs   = cursor + N;                          // N
    int*   sorted = offs + N;                            // E

    const int nb16 = (N + 15) / 16;

    k_enc<<<nb16, 256, 0, stream>>>(x, Wenc, pa, h, N);
    k_mask<<<M, HID, 0, stream>>>(mask, h);
    k_combo<<<18, HID, 0, stream>>>(emb1, emb2, combo);
    k_zero<<<(2 * N + 255) / 256, 256, 0, stream>>>(cnt, 2 * N);   // cnt + cursor
    k_hist<<<(E + 255) / 256, 256, 0, stream>>>(dst, cnt, E);
    k_scan<<<1, 1024, 0, stream>>>(cnt, offs, N);
    k_place<<<(E + 255) / 256, 256, 0, stream>>>(dst, offs, cursor, sorted, E);
    k_gather<<<N, HID, 0, stream>>>(h, src, eattr, combo, offs, cnt, sorted, (float*)d_out);
    k_mlp<<<nb16, 256, 0, stream>>>((float*)d_out, W1, b1, W2, b2, N);
}

// Round 3
// 327.731 us; speedup vs baseline: 4.8710x; 1.4608x over previous
//
#include <hip/hip_runtime.h>

#define HID 128
#define HID2 256

typedef __attribute__((ext_vector_type(8))) short bf16x8;
typedef __attribute__((ext_vector_type(4))) float f32x4;

__device__ inline ushort f2b(float f) {
    union { float f; unsigned u; } v; v.f = f;
    unsigned r = v.u + 0x7FFF + ((v.u >> 16) & 1);
    return (ushort)(r >> 16);
}

// ---------------- cast fp32 -> bf16(ushort) ----------------
__global__ __launch_bounds__(256) void k_cast(const float* __restrict__ in,
                                              ushort* __restrict__ out, int n) {
    int i = blockIdx.x * 256 + threadIdx.x;
    if (i < n) out[i] = f2b(in[i]);
}

// ---------------- kernel 1: h = PReLU(x) @ W_enc^T  (bf16 MFMA) ----------------
// grid ceil(N/32), block 256 (4 waves). LDS: swizzled bf16 [32][128].
__global__ __launch_bounds__(256) void k_enc(const float* __restrict__ x,
                                             const ushort* __restrict__ Wb,
                                             const float* __restrict__ pa,
                                             float* __restrict__ h, int N) {
    __shared__ ushort xs[32 * 128];
    const int t = threadIdx.x;
    const int bn = blockIdx.x * 32;
    const float a = pa[0];
    {
        int colblk = t & 15;
        int r0 = t >> 4;
#pragma unroll
        for (int i = 0; i < 2; ++i) {
            int row = r0 + i * 16;
            int grow = bn + row;
            float vv[8];
            if (grow < N) {
                float4 v0 = *(const float4*)(x + (size_t)grow * HID + colblk * 8);
                float4 v1 = *(const float4*)(x + (size_t)grow * HID + colblk * 8 + 4);
                vv[0]=v0.x; vv[1]=v0.y; vv[2]=v0.z; vv[3]=v0.w;
                vv[4]=v1.x; vv[5]=v1.y; vv[6]=v1.z; vv[7]=v1.w;
            } else {
#pragma unroll
                for (int j = 0; j < 8; ++j) vv[j] = 0.f;
            }
            ushort u[8];
#pragma unroll
            for (int j = 0; j < 8; ++j) {
                float f = vv[j] > 0.f ? vv[j] : a * vv[j];
                u[j] = f2b(f);
            }
            int byte = row * 256 + ((colblk * 16) ^ ((row & 7) << 4));
            *reinterpret_cast<bf16x8*>((char*)xs + byte) = *(bf16x8*)u;
        }
    }
    __syncthreads();
    const int w = t >> 6, l = t & 63;
    const int mt = w >> 1;
    const int nt0 = (w & 1) * 4;
    const int lrow = l & 15, lk = l >> 4;
    bf16x8 afr[4];
#pragma unroll
    for (int ks = 0; ks < 4; ++ks) {
        int row = mt * 16 + lrow;
        int cb = ks * 64 + lk * 16;
        afr[ks] = *(const bf16x8*)((const char*)xs + row * 256 + (cb ^ ((row & 7) << 4)));
    }
#pragma unroll
    for (int i = 0; i < 4; ++i) {
        int nt = nt0 + i;
        int n = nt * 16 + lrow;
        f32x4 acc = {0.f, 0.f, 0.f, 0.f};
#pragma unroll
        for (int ks = 0; ks < 4; ++ks) {
            bf16x8 bfr = *(const bf16x8*)(Wb + n * HID + ks * 32 + lk * 8);
            acc = __builtin_amdgcn_mfma_f32_16x16x32_bf16(afr[ks], bfr, acc, 0, 0, 0);
        }
#pragma unroll
        for (int r = 0; r < 4; ++r) {
            int grow = bn + mt * 16 + lk * 4 + r;
            if (grow < N) h[(size_t)grow * HID + nt * 16 + lrow] = acc[r];
        }
    }
}

// ---------------- kernel 2: zero masked rows ----------------
__global__ void k_mask(const int* __restrict__ idx, float* __restrict__ h) {
    h[idx[blockIdx.x] * HID + threadIdx.x] = 0.f;
}

// ---------------- kernel 3: combo[i][j] = emb1[i] + emb2[j] ----------------
__global__ void k_combo(const float* __restrict__ e1, const float* __restrict__ e2,
                        float* __restrict__ combo) {
    int i = blockIdx.x / 3, j = blockIdx.x % 3, c = threadIdx.x;
    combo[blockIdx.x * HID + c] = e1[i * HID + c] + e2[j * HID + c];
}

// ---------------- kernel 4: zero int scratch ----------------
__global__ __launch_bounds__(256) void k_zero(int* __restrict__ p, int n) {
    int i = blockIdx.x * 256 + threadIdx.x;
    if (i < n) p[i] = 0;
}

// ---------------- kernel 5: histogram of dst ----------------
__global__ __launch_bounds__(256) void k_hist(const int* __restrict__ dst,
                                              int* __restrict__ cnt, int E) {
    int e = blockIdx.x * 256 + threadIdx.x;
    if (e < E) atomicAdd(&cnt[dst[e]], 1);
}

// ---------------- kernel 6: exclusive scan (1 block, 1024 thr) ----------------
__global__ __launch_bounds__(1024) void k_scan(const int* __restrict__ cnt,
                                               int* __restrict__ offs, int N) {
    __shared__ int ls[1024];
    const int t = threadIdx.x;
    const int chunk = (N + 1023) / 1024;
    const int begin = t * chunk;
    const int end = min(begin + chunk, N);
    int s = 0;
    for (int i = begin; i < end; ++i) s += cnt[i];
    ls[t] = s;
    __syncthreads();
    for (int off = 1; off < 1024; off <<= 1) {
        int u = (t >= off) ? ls[t - off] : 0;
        __syncthreads();
        ls[t] += u;
        __syncthreads();
    }
    int run = (t == 0) ? 0 : ls[t - 1];
    for (int i = begin; i < end; ++i) {
        offs[i] = run;
        run += cnt[i];
    }
}

// ---------------- kernel 7: scatter edge ids into dst-sorted order ----------------
__global__ __launch_bounds__(256) void k_place(const int* __restrict__ dst,
                                               const int* __restrict__ offs,
                                               int* __restrict__ cursor,
                                               int* __restrict__ sorted, int E) {
    int e = blockIdx.x * 256 + threadIdx.x;
    if (e < E) {
        int d = dst[e];
        int pos = offs[d] + atomicAdd(&cursor[d], 1);
        sorted[pos] = e;
    }
}

// ---------------- kernel 8: per-node gather-accumulate (incl. self loop) ----------------
__global__ __launch_bounds__(128) void k_gather(const float* __restrict__ h,
                                                const int* __restrict__ src,
                                                const int* __restrict__ ea,
                                                const float* __restrict__ combo,
                                                const int* __restrict__ offs,
                                                const int* __restrict__ cnt,
                                                const int* __restrict__ sorted,
                                                float* __restrict__ out) {
    __shared__ int s_src[128];
    __shared__ int s_cmb[128];
    const int n = blockIdx.x;
    const int c = threadIdx.x;
    const int start = offs[n];
    const int deg = cnt[n];
    float acc = h[n * HID + c] + combo[12 * HID + c];
    for (int base = 0; base < deg; base += 128) {
        int m = min(128, deg - base);
        if (c < m) {
            int e = sorted[start + base + c];
            s_src[c] = src[e];
            s_cmb[c] = ea[2 * e] * 3 + ea[2 * e + 1];
        }
        __syncthreads();
#pragma unroll 4
        for (int k = 0; k < m; ++k) {
            acc += h[s_src[k] * HID + c] + combo[s_cmb[k] * HID + c];
        }
        __syncthreads();
    }
    out[n * HID + c] = acc;
}

// ---------------- kernel 9: MLP via bf16 MFMA, in place on io ----------------
// grid ceil(N/32), block 256. LDS: as[32][128]bf16 swz + hs[32][256]bf16 swz = 24KB.
__global__ __launch_bounds__(256) void k_mlp(float* __restrict__ io,
                                             const ushort* __restrict__ W1b,
                                             const float* __restrict__ b1,
                                             const ushort* __restrict__ W2b,
                                             const float* __restrict__ b2, int N) {
    __shared__ ushort as[32 * 128];
    __shared__ ushort hs[32 * 256];
    const int t = threadIdx.x;
    const int bn = blockIdx.x * 32;
    {
        int colblk = t & 15;
        int r0 = t >> 4;
#pragma unroll
        for (int i = 0; i < 2; ++i) {
            int row = r0 + i * 16;
            int grow = bn + row;
            ushort u[8];
            if (grow < N) {
                float4 v0 = *(const float4*)(io + (size_t)grow * HID + colblk * 8);
                float4 v1 = *(const float4*)(io + (size_t)grow * HID + colblk * 8 + 4);
                u[0]=f2b(v0.x); u[1]=f2b(v0.y); u[2]=f2b(v0.z); u[3]=f2b(v0.w);
                u[4]=f2b(v1.x); u[5]=f2b(v1.y); u[6]=f2b(v1.z); u[7]=f2b(v1.w);
            } else {
#pragma unroll
                for (int j = 0; j < 8; ++j) u[j] = 0;
            }
            int byte = row * 256 + ((colblk * 16) ^ ((row & 7) << 4));
            *reinterpret_cast<bf16x8*>((char*)as + byte) = *(bf16x8*)u;
        }
    }
    __syncthreads();
    const int w = t >> 6, l = t & 63;
    const int lrow = l & 15, lk = l >> 4;
    // ---- layer 1: hidden[32][256] = relu(as @ W1^T + b1), bf16 into hs ----
    {
        const int mt = w >> 1;
        const int ntb = (w & 1) * 8;
        bf16x8 afr[4];
#pragma unroll
        for (int ks = 0; ks < 4; ++ks) {
            int row = mt * 16 + lrow;
            int cb = ks * 64 + lk * 16;
            afr[ks] = *(const bf16x8*)((const char*)as + row * 256 + (cb ^ ((row & 7) << 4)));
        }
#pragma unroll
        for (int i = 0; i < 8; ++i) {
            int nt = ntb + i;
            int n = nt * 16 + lrow;
            f32x4 acc = {0.f, 0.f, 0.f, 0.f};
#pragma unroll
            for (int ks = 0; ks < 4; ++ks) {
                bf16x8 bfr = *(const bf16x8*)(W1b + n * HID + ks * 32 + lk * 8);
                acc = __builtin_amdgcn_mfma_f32_16x16x32_bf16(afr[ks], bfr, acc, 0, 0, 0);
            }
            float bb = b1[n];
#pragma unroll
            for (int r = 0; r < 4; ++r) {
                float v = acc[r] + bb;
                v = v > 0.f ? v : 0.f;
                int row = mt * 16 + lk * 4 + r;
                int byte = row * 512 + ((n * 2) ^ ((row & 7) << 4));
                *(ushort*)((char*)hs + byte) = f2b(v);
            }
        }
    }
    __syncthreads();
    // ---- layer 2: out[32][128] = hs @ W2^T + b2 ----
    {
        const int mt = w >> 1;
        const int ntb = (w & 1) * 4;
        bf16x8 afr[8];
#pragma unroll
        for (int ks = 0; ks < 8; ++ks) {
            int row = mt * 16 + lrow;
            int cb = ks * 64 + lk * 16;
            afr[ks] = *(const bf16x8*)((const char*)hs + row * 512 + (cb ^ ((row & 7) << 4)));
        }
#pragma unroll
        for (int i = 0; i < 4; ++i) {
            int nt = ntb + i;
            int n = nt * 16 + lrow;
            f32x4 acc = {0.f, 0.f, 0.f, 0.f};
#pragma unroll
            for (int ks = 0; ks < 8; ++ks) {
                bf16x8 bfr = *(const bf16x8*)(W2b + n * HID2 + ks * 32 + lk * 8);
                acc = __builtin_amdgcn_mfma_f32_16x16x32_bf16(afr[ks], bfr, acc, 0, 0, 0);
            }
            float bb = b2[n];
#pragma unroll
            for (int r = 0; r < 4; ++r) {
                int grow = bn + mt * 16 + lk * 4 + r;
                if (grow < N) io[(size_t)grow * HID + n] = acc[r] + bb;
            }
        }
    }
}

extern "C" void kernel_launch(void* const* d_in, const int* in_sizes, int n_in,
                              void* d_out, int out_size, void* d_ws, size_t ws_size,
                              hipStream_t stream) {
    const float* x     = (const float*)d_in[0];
    const int*   eidx  = (const int*)d_in[1];
    const int*   eattr = (const int*)d_in[2];
    const int*   mask  = (const int*)d_in[3];
    const float* pa    = (const float*)d_in[4];
    const float* Wenc  = (const float*)d_in[5];
    const float* W1    = (const float*)d_in[6];
    const float* b1    = (const float*)d_in[7];
    const float* W2    = (const float*)d_in[8];
    const float* b2    = (const float*)d_in[9];
    const float* emb1  = (const float*)d_in[10];
    const float* emb2  = (const float*)d_in[11];

    const int N = in_sizes[0] / HID;     // 50000
    const int E = in_sizes[1] / 2;       // 800000
    const int M = in_sizes[3];           // 5000

    const int* src = eidx;
    const int* dst = eidx + E;

    // workspace layout
    float*  h      = (float*)d_ws;                 // N*HID f32
    float*  combo  = h + (size_t)N * HID;          // 18*HID f32
    int*    cnt    = (int*)(combo + 18 * HID);     // N
    int*    cursor = cnt + N;                      // N
    int*    offs   = cursor + N;                   // N
    int*    sorted = offs + N;                     // E
    ushort* Wencb  = (ushort*)(sorted + E);        // 128*128
    ushort* W1b    = Wencb + HID * HID;            // 256*128
    ushort* W2b    = W1b + HID2 * HID;             // 128*256

    const int nb32 = (N + 31) / 32;

    k_cast<<<(HID * HID + 255) / 256, 256, 0, stream>>>(Wenc, Wencb, HID * HID);
    k_cast<<<(HID2 * HID + 255) / 256, 256, 0, stream>>>(W1, W1b, HID2 * HID);
    k_cast<<<(HID * HID2 + 255) / 256, 256, 0, stream>>>(W2, W2b, HID * HID2);

    k_enc<<<nb32, 256, 0, stream>>>(x, Wencb, pa, h, N);
    k_mask<<<M, HID, 0, stream>>>(mask, h);
    k_combo<<<18, HID, 0, stream>>>(emb1, emb2, combo);
    k_zero<<<(2 * N + 255) / 256, 256, 0, stream>>>(cnt, 2 * N);   // cnt + cursor
    k_hist<<<(E + 255) / 256, 256, 0, stream>>>(dst, cnt, E);
    k_scan<<<1, 1024, 0, stream>>>(cnt, offs, N);
    k_place<<<(E + 255) / 256, 256, 0, stream>>>(dst, offs, cursor, sorted, E);
    k_gather<<<N, HID, 0, stream>>>(h, src, eattr, combo, offs, cnt, sorted, (float*)d_out);
    k_mlp<<<nb32, 256, 0, stream>>>((float*)d_out, W1b, b1, W2b, b2, N);
}

// Round 4
// 273.469 us; speedup vs baseline: 5.8375x; 1.1984x over previous
//
#include <hip/hip_runtime.h>

#define HID 128
#define HID2 256

typedef __attribute__((ext_vector_type(8))) short bf16x8;
typedef __attribute__((ext_vector_type(4))) float f32x4;

__device__ inline ushort f2b(float f) {
    union { float f; unsigned u; } v; v.f = f;
    unsigned r = v.u + 0x7FFF + ((v.u >> 16) & 1);
    return (ushort)(r >> 16);
}
__device__ inline float b2f(unsigned hi16) {
    union { unsigned u; float f; } v; v.u = hi16 << 16;
    return v.f;
}

// ---------------- cast all 3 weight matrices fp32 -> bf16 ----------------
#define SZ0 (HID * HID)      // Wenc 16384
#define SZ1 (HID2 * HID)     // W1   32768
#define SZ2 (HID * HID2)     // W2   32768
__global__ __launch_bounds__(256) void k_castw(const float* __restrict__ w0,
                                               const float* __restrict__ w1,
                                               const float* __restrict__ w2,
                                               ushort* __restrict__ o0,
                                               ushort* __restrict__ o1,
                                               ushort* __restrict__ o2) {
    int i = blockIdx.x * 256 + threadIdx.x;
    if (i < SZ0) o0[i] = f2b(w0[i]);
    else if (i < SZ0 + SZ1) o1[i - SZ0] = f2b(w1[i - SZ0]);
    else if (i < SZ0 + SZ1 + SZ2) o2[i - SZ0 - SZ1] = f2b(w2[i - SZ0 - SZ1]);
}

// ---------------- comboT[col][t] = bf16(emb1[t/3][col] + emb2[t%3][col]), t<18 ----------------
// [128][32] bf16, zero-padded t>=18. grid 16, block 256.
__global__ __launch_bounds__(256) void k_combo2(const float* __restrict__ e1,
                                                const float* __restrict__ e2,
                                                ushort* __restrict__ comboT) {
    int i = blockIdx.x * 256 + threadIdx.x;   // < 4096
    int col = i >> 5, tt = i & 31;
    float v = 0.f;
    if (tt < 18) v = e1[(tt / 3) * HID + col] + e2[(tt % 3) * HID + col];
    comboT[col * 32 + tt] = f2b(v);
}

// ---------------- p = bf16(PReLU(x)), 8 elems/thread ----------------
__global__ __launch_bounds__(256) void k_prelu(const float* __restrict__ x,
                                               const float* __restrict__ pa,
                                               ushort* __restrict__ p, int total8) {
    int i = blockIdx.x * 256 + threadIdx.x;
    if (i >= total8) return;
    const float a = pa[0];
    float4 v0 = *(const float4*)(x + (size_t)i * 8);
    float4 v1 = *(const float4*)(x + (size_t)i * 8 + 4);
    float vv[8] = {v0.x, v0.y, v0.z, v0.w, v1.x, v1.y, v1.z, v1.w};
    ushort u[8];
#pragma unroll
    for (int j = 0; j < 8; ++j) {
        float f = vv[j] > 0.f ? vv[j] : a * vv[j];
        u[j] = f2b(f);
    }
    *(bf16x8*)(p + (size_t)i * 8) = *(bf16x8*)u;
}

// ---------------- zero masked rows of p (bf16) ----------------
__global__ void k_mask(const int* __restrict__ idx, ushort* __restrict__ p) {
    *(unsigned*)(p + (size_t)idx[blockIdx.x] * HID + 2 * threadIdx.x) = 0u;  // block=64
}

// ---------------- zero int scratch ----------------
__global__ __launch_bounds__(256) void k_zero(int* __restrict__ q, int n) {
    int i = blockIdx.x * 256 + threadIdx.x;
    if (i < n) q[i] = 0;
}

// ---------------- histogram of dst ----------------
__global__ __launch_bounds__(256) void k_hist(const int* __restrict__ dst,
                                              int* __restrict__ cnt, int E) {
    int e = blockIdx.x * 256 + threadIdx.x;
    if (e < E) atomicAdd(&cnt[dst[e]], 1);
}

// ---------------- exclusive scan (1 block, 1024 thr) ----------------
__global__ __launch_bounds__(1024) void k_scan(const int* __restrict__ cnt,
                                               int* __restrict__ offs, int N) {
    __shared__ int ls[1024];
    const int t = threadIdx.x;
    const int chunk = (N + 1023) / 1024;
    const int begin = t * chunk;
    const int end = min(begin + chunk, N);
    int s = 0;
    for (int i = begin; i < end; ++i) s += cnt[i];
    ls[t] = s;
    __syncthreads();
    for (int off = 1; off < 1024; off <<= 1) {
        int u = (t >= off) ? ls[t - off] : 0;
        __syncthreads();
        ls[t] += u;
        __syncthreads();
    }
    int run = (t == 0) ? 0 : ls[t - 1];
    for (int i = begin; i < end; ++i) {
        offs[i] = run;
        run += cnt[i];
    }
}

// ---------------- place: sorted[pos] = src | (cmb<<27)  (coalesced src/ea reads) ----------------
__global__ __launch_bounds__(256) void k_place(const int* __restrict__ src,
                                               const int* __restrict__ dst,
                                               const int* __restrict__ ea,
                                               const int* __restrict__ offs,
                                               int* __restrict__ cursor,
                                               int* __restrict__ sorted, int E) {
    int e = blockIdx.x * 256 + threadIdx.x;
    if (e < E) {
        int d = dst[e];
        int cmb = ea[2 * e] * 3 + ea[2 * e + 1];
        int pos = offs[d] + atomicAdd(&cursor[d], 1);
        sorted[pos] = src[e] | (cmb << 27);
    }
}

// ---------------- gather: S[n] = p[n] + sum p[src]; counts -> A2 bf16 ----------------
// grid N, block 64; thread owns 2 channels (uint loads)
__global__ __launch_bounds__(64) void k_gather(const ushort* __restrict__ p,
                                               const int* __restrict__ offs,
                                               const int* __restrict__ cnt,
                                               const int* __restrict__ sorted,
                                               ushort* __restrict__ A,
                                               ushort* __restrict__ A2) {
    __shared__ int s_m[64];
    __shared__ int s_c[18];
    const int n = blockIdx.x;
    const int c = threadIdx.x;
    if (c < 18) s_c[c] = (c == 12) ? 1 : 0;   // self-loop combo (4,0) -> 4*3+0
    const int start = offs[n];
    const int deg = cnt[n];
    unsigned pv = *(const unsigned*)(p + (size_t)n * HID + 2 * c);
    float a0 = b2f(pv & 0xffffu), a1 = b2f(pv >> 16);
    __syncthreads();
    for (int base = 0; base < deg; base += 64) {
        int m = min(64, deg - base);
        if (c < m) {
            int v = sorted[start + base + c];
            s_m[c] = v;
            atomicAdd(&s_c[v >> 27], 1);
        }
        __syncthreads();
#pragma unroll 4
        for (int k = 0; k < m; ++k) {
            int u = s_m[k] & 0x07FFFFFF;
            unsigned w = *(const unsigned*)(p + (size_t)u * HID + 2 * c);
            a0 += b2f(w & 0xffffu);
            a1 += b2f(w >> 16);
        }
        __syncthreads();
    }
    *(unsigned*)(A + (size_t)n * HID + 2 * c) = (unsigned)f2b(a0) | ((unsigned)f2b(a1) << 16);
    if (c < 16) {
        int i0 = 2 * c, i1 = 2 * c + 1;
        ushort u0 = (i0 < 18) ? f2b((float)s_c[i0]) : (ushort)0;
        ushort u1 = (i1 < 18) ? f2b((float)s_c[i1]) : (ushort)0;
        *(unsigned*)(A2 + (size_t)n * 32 + 2 * c) = (unsigned)u0 | ((unsigned)u1 << 16);
    }
}

// ---------------- fused: out = relu((S@Wenc^T + cnt@combo)@W1^T + b1)@W2^T + b2 ----------------
// grid ceil(N/32), block 256 (4 waves). LDS 34 KB.
__global__ __launch_bounds__(256) void k_fused(const ushort* __restrict__ A,
                                               const ushort* __restrict__ A2,
                                               const ushort* __restrict__ Wencb,
                                               const ushort* __restrict__ comboT,
                                               const ushort* __restrict__ W1b,
                                               const float* __restrict__ b1,
                                               const ushort* __restrict__ W2b,
                                               const float* __restrict__ b2,
                                               float* __restrict__ out, int N) {
    __shared__ ushort as[32 * 128];   // 8 KB, swz (row&7)<<4
    __shared__ ushort a2s[32 * 32];   // 2 KB, swz (row&3)<<4
    __shared__ ushort h1[32 * 128];   // 8 KB
    __shared__ ushort h2[32 * 256];   // 16 KB
    const int t = threadIdx.x;
    const int bn = blockIdx.x * 32;
    {
        int colblk = t & 15;
        int r0 = t >> 4;
#pragma unroll
        for (int i = 0; i < 2; ++i) {
            int row = r0 + i * 16;
            int grow = bn + row;
            bf16x8 v;
            if (grow < N) v = *(const bf16x8*)(A + (size_t)grow * HID + colblk * 8);
            else { ushort z[8] = {0,0,0,0,0,0,0,0}; v = *(bf16x8*)z; }
            *(bf16x8*)((char*)as + row * 256 + ((colblk * 16) ^ ((row & 7) << 4))) = v;
        }
    }
    if (t < 128) {
        int row = t >> 2, seg = t & 3;
        int grow = bn + row;
        bf16x8 v;
        if (grow < N) v = *(const bf16x8*)(A2 + (size_t)grow * 32 + seg * 8);
        else { ushort z[8] = {0,0,0,0,0,0,0,0}; v = *(bf16x8*)z; }
        *(bf16x8*)((char*)a2s + row * 64 + ((seg * 16) ^ ((row & 3) << 4))) = v;
    }
    __syncthreads();
    const int w = t >> 6, l = t & 63;
    const int lrow = l & 15, lk = l >> 4;
    const int mt = w >> 1;
    // ---- enc: aggr[32][128] = S@Wenc^T + cnt@combo, bf16 -> h1 ----
    {
        const int ntb = (w & 1) * 4;
        const int row = mt * 16 + lrow;
        bf16x8 afr[4], a2fr;
#pragma unroll
        for (int ks = 0; ks < 4; ++ks)
            afr[ks] = *(const bf16x8*)((const char*)as + row * 256 + ((ks * 64 + lk * 16) ^ ((row & 7) << 4)));
        a2fr = *(const bf16x8*)((const char*)a2s + row * 64 + ((lk * 16) ^ ((row & 3) << 4)));
#pragma unroll
        for (int i = 0; i < 4; ++i) {
            int n = (ntb + i) * 16 + lrow;
            f32x4 acc = {0.f, 0.f, 0.f, 0.f};
#pragma unroll
            for (int ks = 0; ks < 4; ++ks) {
                bf16x8 bfr = *(const bf16x8*)(Wencb + n * HID + ks * 32 + lk * 8);
                acc = __builtin_amdgcn_mfma_f32_16x16x32_bf16(afr[ks], bfr, acc, 0, 0, 0);
            }
            {
                bf16x8 bfr = *(const bf16x8*)(comboT + n * 32 + lk * 8);
                acc = __builtin_amdgcn_mfma_f32_16x16x32_bf16(a2fr, bfr, acc, 0, 0, 0);
            }
#pragma unroll
            for (int r = 0; r < 4; ++r) {
                int row2 = mt * 16 + lk * 4 + r;
                *(ushort*)((char*)h1 + row2 * 256 + ((n * 2) ^ ((row2 & 7) << 4))) = f2b(acc[r]);
            }
        }
    }
    __syncthreads();
    // ---- layer1: hidden[32][256] = relu(h1@W1^T + b1) -> h2 ----
    {
        const int ntb = (w & 1) * 8;
        const int row = mt * 16 + lrow;
        bf16x8 afr[4];
#pragma unroll
        for (int ks = 0; ks < 4; ++ks)
            afr[ks] = *(const bf16x8*)((const char*)h1 + row * 256 + ((ks * 64 + lk * 16) ^ ((row & 7) << 4)));
#pragma unroll
        for (int i = 0; i < 8; ++i) {
            int n = (ntb + i) * 16 + lrow;
            f32x4 acc = {0.f, 0.f, 0.f, 0.f};
#pragma unroll
            for (int ks = 0; ks < 4; ++ks) {
                bf16x8 bfr = *(const bf16x8*)(W1b + n * HID + ks * 32 + lk * 8);
                acc = __builtin_amdgcn_mfma_f32_16x16x32_bf16(afr[ks], bfr, acc, 0, 0, 0);
            }
            float bb = b1[n];
#pragma unroll
            for (int r = 0; r < 4; ++r) {
                float v = acc[r] + bb;
                v = v > 0.f ? v : 0.f;
                int row2 = mt * 16 + lk * 4 + r;
                *(ushort*)((char*)h2 + row2 * 512 + ((n * 2) ^ ((row2 & 7) << 4))) = f2b(v);
            }
        }
    }
    __syncthreads();
    // ---- layer2: out[32][128] = h2@W2^T + b2 ----
    {
        const int ntb = (w & 1) * 4;
        const int row = mt * 16 + lrow;
        bf16x8 afr[8];
#pragma unroll
        for (int ks = 0; ks < 8; ++ks)
            afr[ks] = *(const bf16x8*)((const char*)h2 + row * 512 + ((ks * 64 + lk * 16) ^ ((row & 7) << 4)));
#pragma unroll
        for (int i = 0; i < 4; ++i) {
            int n = (ntb + i) * 16 + lrow;
            f32x4 acc = {0.f, 0.f, 0.f, 0.f};
#pragma unroll
            for (int ks = 0; ks < 8; ++ks) {
                bf16x8 bfr = *(const bf16x8*)(W2b + n * HID2 + ks * 32 + lk * 8);
                acc = __builtin_amdgcn_mfma_f32_16x16x32_bf16(afr[ks], bfr, acc, 0, 0, 0);
            }
            float bb = b2[n];
#pragma unroll
            for (int r = 0; r < 4; ++r) {
                int grow = bn + mt * 16 + lk * 4 + r;
                if (grow < N) out[(size_t)grow * HID + n] = acc[r] + bb;
            }
        }
    }
}

extern "C" void kernel_launch(void* const* d_in, const int* in_sizes, int n_in,
                              void* d_out, int out_size, void* d_ws, size_t ws_size,
                              hipStream_t stream) {
    const float* x     = (const float*)d_in[0];
    const int*   eidx  = (const int*)d_in[1];
    const int*   eattr = (const int*)d_in[2];
    const int*   mask  = (const int*)d_in[3];
    const float* pa    = (const float*)d_in[4];
    const float* Wenc  = (const float*)d_in[5];
    const float* W1    = (const float*)d_in[6];
    const float* b1    = (const float*)d_in[7];
    const float* W2    = (const float*)d_in[8];
    const float* b2    = (const float*)d_in[9];
    const float* emb1  = (const float*)d_in[10];
    const float* emb2  = (const float*)d_in[11];

    const int N = in_sizes[0] / HID;     // 50000
    const int E = in_sizes[1] / 2;       // 800000
    const int M = in_sizes[3];           // 5000

    const int* src = eidx;
    const int* dst = eidx + E;

    // workspace layout (all ushort regions have even element counts -> int stays 4B-aligned)
    ushort* p      = (ushort*)d_ws;                    // N*128
    ushort* A      = p + (size_t)N * HID;              // N*128
    ushort* A2     = A + (size_t)N * HID;              // N*32
    ushort* Wencb  = A2 + (size_t)N * 32;              // 16384
    ushort* W1b    = Wencb + SZ0;                      // 32768
    ushort* W2b    = W1b + SZ1;                        // 32768
    ushort* comboT = W2b + SZ2;                        // 4096
    int*    cnt    = (int*)(comboT + 4096);            // N
    int*    cursor = cnt + N;                          // N
    int*    offs   = cursor + N;                       // N
    int*    sorted = offs + N;                         // E

    const int nb32 = (N + 31) / 32;
    const int total8 = N * HID / 8;

    k_castw<<<(SZ0 + SZ1 + SZ2 + 255) / 256, 256, 0, stream>>>(Wenc, W1, W2, Wencb, W1b, W2b);
    k_combo2<<<16, 256, 0, stream>>>(emb1, emb2, comboT);
    k_prelu<<<(total8 + 255) / 256, 256, 0, stream>>>(x, pa, p, total8);
    k_mask<<<M, 64, 0, stream>>>(mask, p);
    k_zero<<<(2 * N + 255) / 256, 256, 0, stream>>>(cnt, 2 * N);   // cnt + cursor
    k_hist<<<(E + 255) / 256, 256, 0, stream>>>(dst, cnt, E);
    k_scan<<<1, 1024, 0, stream>>>(cnt, offs, N);
    k_place<<<(E + 255) / 256, 256, 0, stream>>>(src, dst, eattr, offs, cursor, sorted, E);
    k_gather<<<N, 64, 0, stream>>>(p, offs, cnt, sorted, A, A2);
    k_fused<<<nb32, 256, 0, stream>>>(A, A2, Wencb, comboT, W1b, b1, W2b, b2, (float*)d_out, N);
}

// Round 5
// 205.360 us; speedup vs baseline: 7.7736x; 1.3317x over previous
//
#include <hip/hip_runtime.h>

#define HID 128
#define HID2 256

typedef __attribute__((ext_vector_type(8))) short bf16x8;
typedef __attribute__((ext_vector_type(4))) float f32x4;

__device__ inline ushort f2b(float f) {
    union { float f; unsigned u; } v; v.f = f;
    unsigned r = v.u + 0x7FFF + ((v.u >> 16) & 1);
    return (ushort)(r >> 16);
}
__device__ inline float b2f(unsigned hi16) {
    union { unsigned u; float f; } v; v.u = hi16 << 16;
    return v.f;
}

// ---------------- cast all 3 weight matrices fp32 -> bf16 ----------------
#define SZ0 (HID * HID)      // Wenc 16384
#define SZ1 (HID2 * HID)     // W1   32768
#define SZ2 (HID * HID2)     // W2   32768
__global__ __launch_bounds__(256) void k_castw(const float* __restrict__ w0,
                                               const float* __restrict__ w1,
                                               const float* __restrict__ w2,
                                               ushort* __restrict__ o0,
                                               ushort* __restrict__ o1,
                                               ushort* __restrict__ o2) {
    int i = blockIdx.x * 256 + threadIdx.x;
    if (i < SZ0) o0[i] = f2b(w0[i]);
    else if (i < SZ0 + SZ1) o1[i - SZ0] = f2b(w1[i - SZ0]);
    else if (i < SZ0 + SZ1 + SZ2) o2[i - SZ0 - SZ1] = f2b(w2[i - SZ0 - SZ1]);
}

// ---------------- comboT[col][t] = bf16(emb1[t/3][col] + emb2[t%3][col]), t<18 ----------------
__global__ __launch_bounds__(256) void k_combo2(const float* __restrict__ e1,
                                                const float* __restrict__ e2,
                                                ushort* __restrict__ comboT) {
    int i = blockIdx.x * 256 + threadIdx.x;   // < 4096
    int col = i >> 5, tt = i & 31;
    float v = 0.f;
    if (tt < 18) v = e1[(tt / 3) * HID + col] + e2[(tt % 3) * HID + col];
    comboT[col * 32 + tt] = f2b(v);
}

// ---------------- p = bf16(PReLU(x)), 8 elems/thread ----------------
__global__ __launch_bounds__(256) void k_prelu(const float* __restrict__ x,
                                               const float* __restrict__ pa,
                                               ushort* __restrict__ p, int total8) {
    int i = blockIdx.x * 256 + threadIdx.x;
    if (i >= total8) return;
    const float a = pa[0];
    float4 v0 = *(const float4*)(x + (size_t)i * 8);
    float4 v1 = *(const float4*)(x + (size_t)i * 8 + 4);
    float vv[8] = {v0.x, v0.y, v0.z, v0.w, v1.x, v1.y, v1.z, v1.w};
    ushort u[8];
#pragma unroll
    for (int j = 0; j < 8; ++j) {
        float f = vv[j] > 0.f ? vv[j] : a * vv[j];
        u[j] = f2b(f);
    }
    *(bf16x8*)(p + (size_t)i * 8) = *(bf16x8*)u;
}

// ---------------- zero masked rows of p (bf16) ----------------
__global__ void k_mask(const int* __restrict__ idx, ushort* __restrict__ p) {
    *(unsigned*)(p + (size_t)idx[blockIdx.x] * HID + 2 * threadIdx.x) = 0u;  // block=64
}

// ---------------- zero int scratch ----------------
__global__ __launch_bounds__(256) void k_zero(int* __restrict__ q, int n) {
    int i = blockIdx.x * 256 + threadIdx.x;
    if (i < n) q[i] = 0;
}

// ---------------- histogram of dst ----------------
__global__ __launch_bounds__(256) void k_hist(const int* __restrict__ dst,
                                              int* __restrict__ cnt, int E) {
    int e = blockIdx.x * 256 + threadIdx.x;
    if (e < E) atomicAdd(&cnt[dst[e]], 1);
}

// ---------------- hierarchical exclusive scan, 3 phases ----------------
// A: per-block (256) sum -> bsum
__global__ __launch_bounds__(256) void k_scanA(const int* __restrict__ cnt,
                                               int* __restrict__ bsum, int N) {
    __shared__ int ls[256];
    const int t = threadIdx.x;
    int i = blockIdx.x * 256 + t;
    ls[t] = (i < N) ? cnt[i] : 0;
    __syncthreads();
#pragma unroll
    for (int off = 128; off >= 1; off >>= 1) {
        if (t < off) ls[t] += ls[t + off];
        __syncthreads();
    }
    if (t == 0) bsum[blockIdx.x] = ls[0];
}
// B: 1 block, exclusive scan of nb (<256) blocksums in place
__global__ __launch_bounds__(256) void k_scanB(int* __restrict__ bsum, int nb) {
    __shared__ int ls[256];
    const int t = threadIdx.x;
    ls[t] = (t < nb) ? bsum[t] : 0;
    __syncthreads();
#pragma unroll
    for (int off = 1; off < 256; off <<= 1) {
        int u = (t >= off) ? ls[t - off] : 0;
        __syncthreads();
        ls[t] += u;
        __syncthreads();
    }
    if (t < nb) bsum[t] = (t == 0) ? 0 : ls[t - 1];
}
// C: block-local exclusive scan + block offset
__global__ __launch_bounds__(256) void k_scanC(const int* __restrict__ cnt,
                                               const int* __restrict__ bsum,
                                               int* __restrict__ offs, int N) {
    __shared__ int ls[256];
    const int t = threadIdx.x;
    int i = blockIdx.x * 256 + t;
    int v = (i < N) ? cnt[i] : 0;
    ls[t] = v;
    __syncthreads();
#pragma unroll
    for (int off = 1; off < 256; off <<= 1) {
        int u = (t >= off) ? ls[t - off] : 0;
        __syncthreads();
        ls[t] += u;
        __syncthreads();
    }
    if (i < N) offs[i] = bsum[blockIdx.x] + ((t == 0) ? 0 : ls[t - 1]);
}

// ---------------- place: sorted[pos] = src | (cmb<<27) ----------------
__global__ __launch_bounds__(256) void k_place(const int* __restrict__ src,
                                               const int* __restrict__ dst,
                                               const int* __restrict__ ea,
                                               const int* __restrict__ offs,
                                               int* __restrict__ cursor,
                                               int* __restrict__ sorted, int E) {
    int e = blockIdx.x * 256 + threadIdx.x;
    if (e < E) {
        int d = dst[e];
        int cmb = ea[2 * e] * 3 + ea[2 * e + 1];
        int pos = offs[d] + atomicAdd(&cursor[d], 1);
        sorted[pos] = src[e] | (cmb << 27);
    }
}

// ---------------- gather: S[n] = p[n] + sum p[src]; counts -> A2 bf16 ----------------
__global__ __launch_bounds__(64) void k_gather(const ushort* __restrict__ p,
                                               const int* __restrict__ offs,
                                               const int* __restrict__ cnt,
                                               const int* __restrict__ sorted,
                                               ushort* __restrict__ A,
                                               ushort* __restrict__ A2) {
    __shared__ int s_m[64];
    __shared__ int s_c[18];
    const int n = blockIdx.x;
    const int c = threadIdx.x;
    if (c < 18) s_c[c] = (c == 12) ? 1 : 0;   // self-loop combo (4,0) -> 4*3+0
    const int start = offs[n];
    const int deg = cnt[n];
    unsigned pv = *(const unsigned*)(p + (size_t)n * HID + 2 * c);
    float a0 = b2f(pv & 0xffffu), a1 = b2f(pv >> 16);
    __syncthreads();
    for (int base = 0; base < deg; base += 64) {
        int m = min(64, deg - base);
        if (c < m) {
            int v = sorted[start + base + c];
            s_m[c] = v;
            atomicAdd(&s_c[v >> 27], 1);
        }
        __syncthreads();
#pragma unroll 4
        for (int k = 0; k < m; ++k) {
            int u = s_m[k] & 0x07FFFFFF;
            unsigned w = *(const unsigned*)(p + (size_t)u * HID + 2 * c);
            a0 += b2f(w & 0xffffu);
            a1 += b2f(w >> 16);
        }
        __syncthreads();
    }
    *(unsigned*)(A + (size_t)n * HID + 2 * c) = (unsigned)f2b(a0) | ((unsigned)f2b(a1) << 16);
    if (c < 16) {
        int i0 = 2 * c, i1 = 2 * c + 1;
        ushort u0 = (i0 < 18) ? f2b((float)s_c[i0]) : (ushort)0;
        ushort u1 = (i1 < 18) ? f2b((float)s_c[i1]) : (ushort)0;
        *(unsigned*)(A2 + (size_t)n * 32 + 2 * c) = (unsigned)u0 | ((unsigned)u1 << 16);
    }
}

// ---------------- fused: out = relu((S@Wenc^T + cnt@combo)@W1^T + b1)@W2^T + b2 ----------------
__global__ __launch_bounds__(256) void k_fused(const ushort* __restrict__ A,
                                               const ushort* __restrict__ A2,
                                               const ushort* __restrict__ Wencb,
                                               const ushort* __restrict__ comboT,
                                               const ushort* __restrict__ W1b,
                                               const float* __restrict__ b1,
                                               const ushort* __restrict__ W2b,
                                               const float* __restrict__ b2,
                                               float* __restrict__ out, int N) {
    __shared__ ushort as[32 * 128];   // 8 KB, swz (row&7)<<4
    __shared__ ushort a2s[32 * 32];   // 2 KB, swz (row&3)<<4
    __shared__ ushort h1[32 * 128];   // 8 KB
    __shared__ ushort h2[32 * 256];   // 16 KB
    const int t = threadIdx.x;
    const int bn = blockIdx.x * 32;
    {
        int colblk = t & 15;
        int r0 = t >> 4;
#pragma unroll
        for (int i = 0; i < 2; ++i) {
            int row = r0 + i * 16;
            int grow = bn + row;
            bf16x8 v;
            if (grow < N) v = *(const bf16x8*)(A + (size_t)grow * HID + colblk * 8);
            else { ushort z[8] = {0,0,0,0,0,0,0,0}; v = *(bf16x8*)z; }
            *(bf16x8*)((char*)as + row * 256 + ((colblk * 16) ^ ((row & 7) << 4))) = v;
        }
    }
    if (t < 128) {
        int row = t >> 2, seg = t & 3;
        int grow = bn + row;
        bf16x8 v;
        if (grow < N) v = *(const bf16x8*)(A2 + (size_t)grow * 32 + seg * 8);
        else { ushort z[8] = {0,0,0,0,0,0,0,0}; v = *(bf16x8*)z; }
        *(bf16x8*)((char*)a2s + row * 64 + ((seg * 16) ^ ((row & 3) << 4))) = v;
    }
    __syncthreads();
    const int w = t >> 6, l = t & 63;
    const int lrow = l & 15, lk = l >> 4;
    const int mt = w >> 1;
    // ---- enc: aggr[32][128] = S@Wenc^T + cnt@combo, bf16 -> h1 ----
    {
        const int ntb = (w & 1) * 4;
        const int row = mt * 16 + lrow;
        bf16x8 afr[4], a2fr;
#pragma unroll
        for (int ks = 0; ks < 4; ++ks)
            afr[ks] = *(const bf16x8*)((const char*)as + row * 256 + ((ks * 64 + lk * 16) ^ ((row & 7) << 4)));
        a2fr = *(const bf16x8*)((const char*)a2s + row * 64 + ((lk * 16) ^ ((row & 3) << 4)));
#pragma unroll
        for (int i = 0; i < 4; ++i) {
            int n = (ntb + i) * 16 + lrow;
            f32x4 acc = {0.f, 0.f, 0.f, 0.f};
#pragma unroll
            for (int ks = 0; ks < 4; ++ks) {
                bf16x8 bfr = *(const bf16x8*)(Wencb + n * HID + ks * 32 + lk * 8);
                acc = __builtin_amdgcn_mfma_f32_16x16x32_bf16(afr[ks], bfr, acc, 0, 0, 0);
            }
            {
                bf16x8 bfr = *(const bf16x8*)(comboT + n * 32 + lk * 8);
                acc = __builtin_amdgcn_mfma_f32_16x16x32_bf16(a2fr, bfr, acc, 0, 0, 0);
            }
#pragma unroll
            for (int r = 0; r < 4; ++r) {
                int row2 = mt * 16 + lk * 4 + r;
                *(ushort*)((char*)h1 + row2 * 256 + ((n * 2) ^ ((row2 & 7) << 4))) = f2b(acc[r]);
            }
        }
    }
    __syncthreads();
    // ---- layer1: hidden[32][256] = relu(h1@W1^T + b1) -> h2 ----
    {
        const int ntb = (w & 1) * 8;
        const int row = mt * 16 + lrow;
        bf16x8 afr[4];
#pragma unroll
        for (int ks = 0; ks < 4; ++ks)
            afr[ks] = *(const bf16x8*)((const char*)h1 + row * 256 + ((ks * 64 + lk * 16) ^ ((row & 7) << 4)));
#pragma unroll
        for (int i = 0; i < 8; ++i) {
            int n = (ntb + i) * 16 + lrow;
            f32x4 acc = {0.f, 0.f, 0.f, 0.f};
#pragma unroll
            for (int ks = 0; ks < 4; ++ks) {
                bf16x8 bfr = *(const bf16x8*)(W1b + n * HID + ks * 32 + lk * 8);
                acc = __builtin_amdgcn_mfma_f32_16x16x32_bf16(afr[ks], bfr, acc, 0, 0, 0);
            }
            float bb = b1[n];
#pragma unroll
            for (int r = 0; r < 4; ++r) {
                float v = acc[r] + bb;
                v = v > 0.f ? v : 0.f;
                int row2 = mt * 16 + lk * 4 + r;
                *(ushort*)((char*)h2 + row2 * 512 + ((n * 2) ^ ((row2 & 7) << 4))) = f2b(v);
            }
        }
    }
    __syncthreads();
    // ---- layer2: out[32][128] = h2@W2^T + b2 ----
    {
        const int ntb = (w & 1) * 4;
        const int row = mt * 16 + lrow;
        bf16x8 afr[8];
#pragma unroll
        for (int ks = 0; ks < 8; ++ks)
            afr[ks] = *(const bf16x8*)((const char*)h2 + row * 512 + ((ks * 64 + lk * 16) ^ ((row & 7) << 4)));
#pragma unroll
        for (int i = 0; i < 4; ++i) {
            int n = (ntb + i) * 16 + lrow;
            f32x4 acc = {0.f, 0.f, 0.f, 0.f};
#pragma unroll
            for (int ks = 0; ks < 8; ++ks) {
                bf16x8 bfr = *(const bf16x8*)(W2b + n * HID2 + ks * 32 + lk * 8);
                acc = __builtin_amdgcn_mfma_f32_16x16x32_bf16(afr[ks], bfr, acc, 0, 0, 0);
            }
            float bb = b2[n];
#pragma unroll
            for (int r = 0; r < 4; ++r) {
                int grow = bn + mt * 16 + lk * 4 + r;
                if (grow < N) out[(size_t)grow * HID + n] = acc[r] + bb;
            }
        }
    }
}

extern "C" void kernel_launch(void* const* d_in, const int* in_sizes, int n_in,
                              void* d_out, int out_size, void* d_ws, size_t ws_size,
                              hipStream_t stream) {
    const float* x     = (const float*)d_in[0];
    const int*   eidx  = (const int*)d_in[1];
    const int*   eattr = (const int*)d_in[2];
    const int*   mask  = (const int*)d_in[3];
    const float* pa    = (const float*)d_in[4];
    const float* Wenc  = (const float*)d_in[5];
    const float* W1    = (const float*)d_in[6];
    const float* b1    = (const float*)d_in[7];
    const float* W2    = (const float*)d_in[8];
    const float* b2    = (const float*)d_in[9];
    const float* emb1  = (const float*)d_in[10];
    const float* emb2  = (const float*)d_in[11];

    const int N = in_sizes[0] / HID;     // 50000
    const int E = in_sizes[1] / 2;       // 800000
    const int M = in_sizes[3];           // 5000

    const int* src = eidx;
    const int* dst = eidx + E;

    // workspace layout
    ushort* p      = (ushort*)d_ws;                    // N*128
    ushort* A      = p + (size_t)N * HID;              // N*128
    ushort* A2     = A + (size_t)N * HID;              // N*32
    ushort* Wencb  = A2 + (size_t)N * 32;              // 16384
    ushort* W1b    = Wencb + SZ0;                      // 32768
    ushort* W2b    = W1b + SZ1;                        // 32768
    ushort* comboT = W2b + SZ2;                        // 4096
    int*    cnt    = (int*)(comboT + 4096);            // N
    int*    cursor = cnt + N;                          // N
    int*    offs   = cursor + N;                       // N
    int*    bsum   = offs + N;                         // 256
    int*    sorted = bsum + 256;                       // E

    const int nb32 = (N + 31) / 32;
    const int total8 = N * HID / 8;
    const int nbScan = (N + 255) / 256;                // 196

    k_castw<<<(SZ0 + SZ1 + SZ2 + 255) / 256, 256, 0, stream>>>(Wenc, W1, W2, Wencb, W1b, W2b);
    k_combo2<<<16, 256, 0, stream>>>(emb1, emb2, comboT);
    k_prelu<<<(total8 + 255) / 256, 256, 0, stream>>>(x, pa, p, total8);
    k_mask<<<M, 64, 0, stream>>>(mask, p);
    k_zero<<<(2 * N + 255) / 256, 256, 0, stream>>>(cnt, 2 * N);   // cnt + cursor
    k_hist<<<(E + 255) / 256, 256, 0, stream>>>(dst, cnt, E);
    k_scanA<<<nbScan, 256, 0, stream>>>(cnt, bsum, N);
    k_scanB<<<1, 256, 0, stream>>>(bsum, nbScan);
    k_scanC<<<nbScan, 256, 0, stream>>>(cnt, bsum, offs, N);
    k_place<<<(E + 255) / 256, 256, 0, stream>>>(src, dst, eattr, offs, cursor, sorted, E);
    k_gather<<<N, 64, 0, stream>>>(p, offs, cnt, sorted, A, A2);
    k_fused<<<nb32, 256, 0, stream>>>(A, A2, Wencb, comboT, W1b, b1, W2b, b2, (float*)d_out, N);
}

// Round 6
// 178.589 us; speedup vs baseline: 8.9388x; 1.1499x over previous
//
#include <hip/hip_runtime.h>

#define HID 128
#define HID2 256

typedef __attribute__((ext_vector_type(8))) short bf16x8;
typedef __attribute__((ext_vector_type(4))) float f32x4;

__device__ inline ushort f2b(float f) {
    union { float f; unsigned u; } v; v.f = f;
    unsigned r = v.u + 0x7FFF + ((v.u >> 16) & 1);
    return (ushort)(r >> 16);
}
__device__ inline float b2f(unsigned hi16) {
    union { unsigned u; float f; } v; v.u = hi16 << 16;
    return v.f;
}

// ---------------- cast all 3 weight matrices fp32 -> bf16 ----------------
#define SZ0 (HID * HID)      // Wenc 16384
#define SZ1 (HID2 * HID)     // W1   32768
#define SZ2 (HID * HID2)     // W2   32768
__global__ __launch_bounds__(256) void k_castw(const float* __restrict__ w0,
                                               const float* __restrict__ w1,
                                               const float* __restrict__ w2,
                                               ushort* __restrict__ o0,
                                               ushort* __restrict__ o1,
                                               ushort* __restrict__ o2) {
    int i = blockIdx.x * 256 + threadIdx.x;
    if (i < SZ0) o0[i] = f2b(w0[i]);
    else if (i < SZ0 + SZ1) o1[i - SZ0] = f2b(w1[i - SZ0]);
    else if (i < SZ0 + SZ1 + SZ2) o2[i - SZ0 - SZ1] = f2b(w2[i - SZ0 - SZ1]);
}

// ---------------- comboT[col][t] = bf16(emb1[t/3][col] + emb2[t%3][col]), t<18 ----------------
__global__ __launch_bounds__(256) void k_combo2(const float* __restrict__ e1,
                                                const float* __restrict__ e2,
                                                ushort* __restrict__ comboT) {
    int i = blockIdx.x * 256 + threadIdx.x;   // < 4096
    int col = i >> 5, tt = i & 31;
    float v = 0.f;
    if (tt < 18) v = e1[(tt / 3) * HID + col] + e2[(tt % 3) * HID + col];
    comboT[col * 32 + tt] = f2b(v);
}

// ---------------- p = bf16(PReLU(x)), 8 elems/thread ----------------
__global__ __launch_bounds__(256) void k_prelu(const float* __restrict__ x,
                                               const float* __restrict__ pa,
                                               ushort* __restrict__ p, int total8) {
    int i = blockIdx.x * 256 + threadIdx.x;
    if (i >= total8) return;
    const float a = pa[0];
    float4 v0 = *(const float4*)(x + (size_t)i * 8);
    float4 v1 = *(const float4*)(x + (size_t)i * 8 + 4);
    float vv[8] = {v0.x, v0.y, v0.z, v0.w, v1.x, v1.y, v1.z, v1.w};
    ushort u[8];
#pragma unroll
    for (int j = 0; j < 8; ++j) {
        float f = vv[j] > 0.f ? vv[j] : a * vv[j];
        u[j] = f2b(f);
    }
    *(bf16x8*)(p + (size_t)i * 8) = *(bf16x8*)u;
}

// ---------------- zero masked rows of p (bf16) ----------------
__global__ void k_mask(const int* __restrict__ idx, ushort* __restrict__ p) {
    *(unsigned*)(p + (size_t)idx[blockIdx.x] * HID + 2 * threadIdx.x) = 0u;  // block=64
}

// ---------------- zero int scratch ----------------
__global__ __launch_bounds__(256) void k_zero(int* __restrict__ q, int n) {
    int i = blockIdx.x * 256 + threadIdx.x;
    if (i < n) q[i] = 0;
}

// ---------------- histogram of dst ----------------
__global__ __launch_bounds__(256) void k_hist(const int* __restrict__ dst,
                                              int* __restrict__ cnt, int E) {
    int e = blockIdx.x * 256 + threadIdx.x;
    if (e < E) atomicAdd(&cnt[dst[e]], 1);
}

// ---------------- hierarchical exclusive scan, 3 phases ----------------
__global__ __launch_bounds__(256) void k_scanA(const int* __restrict__ cnt,
                                               int* __restrict__ bsum, int N) {
    __shared__ int ls[256];
    const int t = threadIdx.x;
    int i = blockIdx.x * 256 + t;
    ls[t] = (i < N) ? cnt[i] : 0;
    __syncthreads();
#pragma unroll
    for (int off = 128; off >= 1; off >>= 1) {
        if (t < off) ls[t] += ls[t + off];
        __syncthreads();
    }
    if (t == 0) bsum[blockIdx.x] = ls[0];
}
__global__ __launch_bounds__(256) void k_scanB(int* __restrict__ bsum, int nb) {
    __shared__ int ls[256];
    const int t = threadIdx.x;
    ls[t] = (t < nb) ? bsum[t] : 0;
    __syncthreads();
#pragma unroll
    for (int off = 1; off < 256; off <<= 1) {
        int u = (t >= off) ? ls[t - off] : 0;
        __syncthreads();
        ls[t] += u;
        __syncthreads();
    }
    if (t < nb) bsum[t] = (t == 0) ? 0 : ls[t - 1];
}
__global__ __launch_bounds__(256) void k_scanC(const int* __restrict__ cnt,
                                               const int* __restrict__ bsum,
                                               int* __restrict__ offs, int N) {
    __shared__ int ls[256];
    const int t = threadIdx.x;
    int i = blockIdx.x * 256 + t;
    int v = (i < N) ? cnt[i] : 0;
    ls[t] = v;
    __syncthreads();
#pragma unroll
    for (int off = 1; off < 256; off <<= 1) {
        int u = (t >= off) ? ls[t - off] : 0;
        __syncthreads();
        ls[t] += u;
        __syncthreads();
    }
    if (i < N) offs[i] = bsum[blockIdx.x] + ((t == 0) ? 0 : ls[t - 1]);
}

// ---------------- place: sorted[pos] = src | (cmb<<27) ----------------
__global__ __launch_bounds__(256) void k_place(const int* __restrict__ src,
                                               const int* __restrict__ dst,
                                               const int* __restrict__ ea,
                                               const int* __restrict__ offs,
                                               int* __restrict__ cursor,
                                               int* __restrict__ sorted, int E) {
    int e = blockIdx.x * 256 + threadIdx.x;
    if (e < E) {
        int d = dst[e];
        int cmb = ea[2 * e] * 3 + ea[2 * e + 1];
        int pos = offs[d] + atomicAdd(&cursor[d], 1);
        sorted[pos] = src[e] | (cmb << 27);
    }
}

// ---------------- gather: S[n] = p[n] + sum p[src]; counts -> A2 bf16 ----------------
__global__ __launch_bounds__(64) void k_gather(const ushort* __restrict__ p,
                                               const int* __restrict__ offs,
                                               const int* __restrict__ cnt,
                                               const int* __restrict__ sorted,
                                               ushort* __restrict__ A,
                                               ushort* __restrict__ A2) {
    __shared__ int s_m[64];
    __shared__ int s_c[18];
    const int n = blockIdx.x;
    const int c = threadIdx.x;
    if (c < 18) s_c[c] = (c == 12) ? 1 : 0;   // self-loop combo (4,0) -> 4*3+0
    const int start = offs[n];
    const int deg = cnt[n];
    unsigned pv = *(const unsigned*)(p + (size_t)n * HID + 2 * c);
    float a0 = b2f(pv & 0xffffu), a1 = b2f(pv >> 16);
    __syncthreads();
    for (int base = 0; base < deg; base += 64) {
        int m = min(64, deg - base);
        if (c < m) {
            int v = sorted[start + base + c];
            s_m[c] = v;
            atomicAdd(&s_c[v >> 27], 1);
        }
        __syncthreads();
#pragma unroll 4
        for (int k = 0; k < m; ++k) {
            int u = s_m[k] & 0x07FFFFFF;
            unsigned w = *(const unsigned*)(p + (size_t)u * HID + 2 * c);
            a0 += b2f(w & 0xffffu);
            a1 += b2f(w >> 16);
        }
        __syncthreads();
    }
    *(unsigned*)(A + (size_t)n * HID + 2 * c) = (unsigned)f2b(a0) | ((unsigned)f2b(a1) << 16);
    if (c < 16) {
        int i0 = 2 * c, i1 = 2 * c + 1;
        ushort u0 = (i0 < 18) ? f2b((float)s_c[i0]) : (ushort)0;
        ushort u1 = (i1 < 18) ? f2b((float)s_c[i1]) : (ushort)0;
        *(unsigned*)(A2 + (size_t)n * 32 + 2 * c) = (unsigned)u0 | ((unsigned)u1 << 16);
    }
}

// ---------------- fused MLP: 64 rows/block, weights register-cached per phase ----------------
// LDS 52KB: as[64][128]@0 (16K), a2s[64][32]@16K (4K), h1[64][128]@20K (16K),
//           h2a[64][128]@0 (overlaps dead as), h2b[64][128]@36K (16K)
__global__ __launch_bounds__(256) void k_fused(const ushort* __restrict__ A,
                                               const ushort* __restrict__ A2,
                                               const ushort* __restrict__ Wencb,
                                               const ushort* __restrict__ comboT,
                                               const ushort* __restrict__ W1b,
                                               const float* __restrict__ b1,
                                               const ushort* __restrict__ W2b,
                                               const float* __restrict__ b2,
                                               float* __restrict__ out, int N) {
    __shared__ char smem[53248];
    const int t = threadIdx.x;
    const int bn = blockIdx.x * 64;
    // stage A -> as (swz8)
    {
        int seg = t & 15, r0 = t >> 4;
#pragma unroll
        for (int i = 0; i < 4; ++i) {
            int row = r0 + i * 16;
            int grow = bn + row;
            bf16x8 v;
            if (grow < N) v = *(const bf16x8*)(A + (size_t)grow * HID + seg * 8);
            else { ushort z[8] = {0,0,0,0,0,0,0,0}; v = *(bf16x8*)z; }
            *(bf16x8*)(smem + row * 256 + ((seg * 16) ^ ((row & 7) << 4))) = v;
        }
    }
    // stage A2 -> a2s (swz4)
    {
        int row = t >> 2, seg = t & 3;
        int grow = bn + row;
        bf16x8 v;
        if (grow < N) v = *(const bf16x8*)(A2 + (size_t)grow * 32 + seg * 8);
        else { ushort z[8] = {0,0,0,0,0,0,0,0}; v = *(bf16x8*)z; }
        *(bf16x8*)(smem + 16384 + row * 64 + ((seg * 16) ^ ((row & 3) << 4))) = v;
    }
    __syncthreads();
    const int w = t >> 6, l = t & 63;
    const int lrow = l & 15, lk = l >> 4;
    // ---- enc: h1 = A@Wenc^T + A2@combo  (wave owns n-tiles 2w, 2w+1) ----
    {
        bf16x8 wf[2][4], cf[2];
#pragma unroll
        for (int j = 0; j < 2; ++j) {
            int n = (2 * w + j) * 16 + lrow;
#pragma unroll
            for (int ks = 0; ks < 4; ++ks)
                wf[j][ks] = *(const bf16x8*)(Wencb + n * HID + ks * 32 + lk * 8);
            cf[j] = *(const bf16x8*)(comboT + n * 32 + lk * 8);
        }
#pragma unroll
        for (int rt = 0; rt < 4; ++rt) {
            int arow = rt * 16 + lrow;
            bf16x8 af[4], a2f;
#pragma unroll
            for (int ks = 0; ks < 4; ++ks)
                af[ks] = *(const bf16x8*)(smem + arow * 256 + ((ks * 64 + lk * 16) ^ ((arow & 7) << 4)));
            a2f = *(const bf16x8*)(smem + 16384 + arow * 64 + ((lk * 16) ^ ((arow & 3) << 4)));
#pragma unroll
            for (int j = 0; j < 2; ++j) {
                f32x4 acc = {0.f, 0.f, 0.f, 0.f};
#pragma unroll
                for (int ks = 0; ks < 4; ++ks)
                    acc = __builtin_amdgcn_mfma_f32_16x16x32_bf16(af[ks], wf[j][ks], acc, 0, 0, 0);
                acc = __builtin_amdgcn_mfma_f32_16x16x32_bf16(a2f, cf[j], acc, 0, 0, 0);
                int n = (2 * w + j) * 16 + lrow;
#pragma unroll
                for (int r = 0; r < 4; ++r) {
                    int row2 = rt * 16 + lk * 4 + r;
                    *(ushort*)(smem + 20480 + row2 * 256 + ((2 * n) ^ ((row2 & 7) << 4))) = f2b(acc[r]);
                }
            }
        }
    }
    __syncthreads();
    // ---- layer1: h2 = relu(h1@W1^T + b1)  (wave owns n-tiles 4w..4w+3) ----
    {
        bf16x8 wf[4][4];
        float bb[4];
#pragma unroll
        for (int j = 0; j < 4; ++j) {
            int n = (4 * w + j) * 16 + lrow;
#pragma unroll
            for (int ks = 0; ks < 4; ++ks)
                wf[j][ks] = *(const bf16x8*)(W1b + n * HID + ks * 32 + lk * 8);
            bb[j] = b1[n];
        }
        const int h2base = (w < 2) ? 0 : 36864;
        const int colbase = (w < 2) ? 0 : 128;
#pragma unroll
        for (int rt = 0; rt < 4; ++rt) {
            int arow = rt * 16 + lrow;
            bf16x8 af[4];
#pragma unroll
            for (int ks = 0; ks < 4; ++ks)
                af[ks] = *(const bf16x8*)(smem + 20480 + arow * 256 + ((ks * 64 + lk * 16) ^ ((arow & 7) << 4)));
#pragma unroll
            for (int j = 0; j < 4; ++j) {
                f32x4 acc = {0.f, 0.f, 0.f, 0.f};
#pragma unroll
                for (int ks = 0; ks < 4; ++ks)
                    acc = __builtin_amdgcn_mfma_f32_16x16x32_bf16(af[ks], wf[j][ks], acc, 0, 0, 0);
                int cl = (4 * w + j) * 16 + lrow - colbase;
#pragma unroll
                for (int r = 0; r < 4; ++r) {
                    float v = acc[r] + bb[j];
                    v = v > 0.f ? v : 0.f;
                    int row2 = rt * 16 + lk * 4 + r;
                    *(ushort*)(smem + h2base + row2 * 256 + ((2 * cl) ^ ((row2 & 7) << 4))) = f2b(v);
                }
            }
        }
    }
    __syncthreads();
    // ---- layer2: out = h2@W2^T + b2  (wave owns n-tiles 2w, 2w+1) ----
    {
        bf16x8 wf[2][8];
        float bb[2];
#pragma unroll
        for (int j = 0; j < 2; ++j) {
            int n = (2 * w + j) * 16 + lrow;
#pragma unroll
            for (int ks = 0; ks < 8; ++ks)
                wf[j][ks] = *(const bf16x8*)(W2b + n * HID2 + ks * 32 + lk * 8);
            bb[j] = b2[n];
        }
#pragma unroll
        for (int rt = 0; rt < 4; ++rt) {
            int arow = rt * 16 + lrow;
            bf16x8 af[8];
#pragma unroll
            for (int ks = 0; ks < 4; ++ks)
                af[ks] = *(const bf16x8*)(smem + arow * 256 + ((ks * 64 + lk * 16) ^ ((arow & 7) << 4)));
#pragma unroll
            for (int ks = 4; ks < 8; ++ks)
                af[ks] = *(const bf16x8*)(smem + 36864 + arow * 256 + (((ks - 4) * 64 + lk * 16) ^ ((arow & 7) << 4)));
#pragma unroll
            for (int j = 0; j < 2; ++j) {
                f32x4 acc = {0.f, 0.f, 0.f, 0.f};
#pragma unroll
                for (int ks = 0; ks < 8; ++ks)
                    acc = __builtin_amdgcn_mfma_f32_16x16x32_bf16(af[ks], wf[j][ks], acc, 0, 0, 0);
                int n = (2 * w + j) * 16 + lrow;
#pragma unroll
                for (int r = 0; r < 4; ++r) {
                    int grow = bn + rt * 16 + lk * 4 + r;
                    if (grow < N) out[(size_t)grow * HID + n] = acc[r] + bb[j];
                }
            }
        }
    }
}

extern "C" void kernel_launch(void* const* d_in, const int* in_sizes, int n_in,
                              void* d_out, int out_size, void* d_ws, size_t ws_size,
                              hipStream_t stream) {
    const float* x     = (const float*)d_in[0];
    const int*   eidx  = (const int*)d_in[1];
    const int*   eattr = (const int*)d_in[2];
    const int*   mask  = (const int*)d_in[3];
    const float* pa    = (const float*)d_in[4];
    const float* Wenc  = (const float*)d_in[5];
    const float* W1    = (const float*)d_in[6];
    const float* b1    = (const float*)d_in[7];
    const float* W2    = (const float*)d_in[8];
    const float* b2    = (const float*)d_in[9];
    const float* emb1  = (const float*)d_in[10];
    const float* emb2  = (const float*)d_in[11];

    const int N = in_sizes[0] / HID;     // 50000
    const int E = in_sizes[1] / 2;       // 800000
    const int M = in_sizes[3];           // 5000

    const int* src = eidx;
    const int* dst = eidx + E;

    // workspace layout
    ushort* p      = (ushort*)d_ws;                    // N*128
    ushort* A      = p + (size_t)N * HID;              // N*128
    ushort* A2     = A + (size_t)N * HID;              // N*32
    ushort* Wencb  = A2 + (size_t)N * 32;              // 16384
    ushort* W1b    = Wencb + SZ0;                      // 32768
    ushort* W2b    = W1b + SZ1;                        // 32768
    ushort* comboT = W2b + SZ2;                        // 4096
    int*    cnt    = (int*)(comboT + 4096);            // N
    int*    cursor = cnt + N;                          // N
    int*    offs   = cursor + N;                       // N
    int*    bsum   = offs + N;                         // 256
    int*    sorted = bsum + 256;                       // E

    const int nb64 = (N + 63) / 64;
    const int total8 = N * HID / 8;
    const int nbScan = (N + 255) / 256;                // 196

    k_castw<<<(SZ0 + SZ1 + SZ2 + 255) / 256, 256, 0, stream>>>(Wenc, W1, W2, Wencb, W1b, W2b);
    k_combo2<<<16, 256, 0, stream>>>(emb1, emb2, comboT);
    k_prelu<<<(total8 + 255) / 256, 256, 0, stream>>>(x, pa, p, total8);
    k_mask<<<M, 64, 0, stream>>>(mask, p);
    k_zero<<<(2 * N + 255) / 256, 256, 0, stream>>>(cnt, 2 * N);   // cnt + cursor
    k_hist<<<(E + 255) / 256, 256, 0, stream>>>(dst, cnt, E);
    k_scanA<<<nbScan, 256, 0, stream>>>(cnt, bsum, N);
    k_scanB<<<1, 256, 0, stream>>>(bsum, nbScan);
    k_scanC<<<nbScan, 256, 0, stream>>>(cnt, bsum, offs, N);
    k_place<<<(E + 255) / 256, 256, 0, stream>>>(src, dst, eattr, offs, cursor, sorted, E);
    k_gather<<<N, 64, 0, stream>>>(p, offs, cnt, sorted, A, A2);
    k_fused<<<nb64, 256, 0, stream>>>(A, A2, Wencb, comboT, W1b, b1, W2b, b2, (float*)d_out, N);
}